// Round 10
// baseline (201.086 us; speedup 1.0000x reference)
//
#include <hip/hip_runtime.h>

// CausalSelfAttention: B=2, T=2048, C=1024, H=16, HD=64.
// Inputs/outputs f32; internal bf16 MFMA.
//
// Pipeline:
//   0. cast x f32 -> xb bf16
//   1. transpose+cast w_attn -> wattnT bf16 [3072,1024]
//   2. transpose+cast w_proj -> wprojT bf16
//   3. gemm_bt<QKV> (global_load_lds): xb @ wattnT^T + b_attn -> Q,K,V
//      bf16 [B,H,T,64]   (K pre-scaled by 0.125*log2e)
//   4. transpose_v: V -> Vt [bh][d][t]
//   5. attn_split: PAIRED split-kv flash attention. Each block owns TWO
//      adjacent 64-row q-tiles (2p, 2p+1) x one kv slice (<=8 tiles): the
//      staged K/V LDS tile and its fragments are shared by both q-sets
//      (2x MFMA per LDS byte). S^T formulation, no-max softmax, partials
//      combine by pure addition.
//   6. attn_combine: sum <=4 partials over 128 rows, divide, write Y bf16
//   7. gemm_bt<PLAIN>: Y @ wprojT^T + b_proj -> out f32

typedef unsigned short u16;
typedef unsigned short u16x8 __attribute__((ext_vector_type(8)));
typedef __bf16 bf16x8 __attribute__((ext_vector_type(8)));
typedef __bf16 bf16x4 __attribute__((ext_vector_type(4)));
typedef float f32x4 __attribute__((ext_vector_type(4)));

#define MFMA16(a, b, c) __builtin_amdgcn_mfma_f32_16x16x32_bf16(a, b, c, 0, 0, 0)

static __device__ __forceinline__ u16 f2b(float f) {
  union { float f; unsigned int i; } x; x.f = f;
  unsigned int r = x.i + 0x7fffu + ((x.i >> 16) & 1u);  // RNE
  return (u16)(r >> 16);
}
static __device__ __forceinline__ float b2f(u16 u) {
  union { unsigned int i; float f; } x; x.i = ((unsigned int)u) << 16; return x.f;
}

static __device__ __forceinline__ void gload_lds16(const u16* g, u16* l) {
#if defined(__HIP_DEVICE_COMPILE__)
  __builtin_amdgcn_global_load_lds(
      (const __attribute__((address_space(1))) unsigned int*)g,
      (__attribute__((address_space(3))) unsigned int*)l,
      16, 0, 0);
#else
  (void)g; (void)l;
#endif
}

// ---------------------------------------------------------------- cast
__global__ __launch_bounds__(256) void cast_f32_bf16(
    const float* __restrict__ in, u16* __restrict__ out) {
  int i = (blockIdx.x * 256 + threadIdx.x) * 8;
  float4 a = *(const float4*)&in[i];
  float4 b = *(const float4*)&in[i + 4];
  u16x8 o;
  o[0] = f2b(a.x); o[1] = f2b(a.y); o[2] = f2b(a.z); o[3] = f2b(a.w);
  o[4] = f2b(b.x); o[5] = f2b(b.y); o[6] = f2b(b.z); o[7] = f2b(b.w);
  *(u16x8*)&out[i] = o;
}

// ---------------------------------------------------------------- transpose
__global__ __launch_bounds__(256) void transpose_f32_bf16(
    const float* __restrict__ in, u16* __restrict__ out, int R, int Cc) {
  __shared__ u16 tile[32][33];
  int bx = blockIdx.x, by = blockIdx.y;
  int tx = threadIdx.x, ty = threadIdx.y;
#pragma unroll
  for (int i = 0; i < 4; i++) {
    int r = by * 32 + ty + i * 8;
    int c = bx * 32 + tx;
    tile[ty + i * 8][tx] = f2b(in[r * Cc + c]);
  }
  __syncthreads();
#pragma unroll
  for (int i = 0; i < 4; i++) {
    int r = bx * 32 + ty + i * 8;
    int c = by * 32 + tx;
    out[r * R + c] = tile[tx][ty + i * 8];
  }
}

// V [32][2048][64] -> Vt [32][64][2048].
__global__ __launch_bounds__(256) void transpose_v(
    const u16* __restrict__ in, u16* __restrict__ out) {
  int bh = blockIdx.y;
  int t = blockIdx.x * 128 + (threadIdx.x & 127);
  int dg = (threadIdx.x >> 7) * 32;
  const u16* src = in + (bh * 2048 + t) * 64;
  u16* dst = out + bh * 64 * 2048 + t;
#pragma unroll
  for (int i = 0; i < 32; i++) {
    int d = dg + i;
    dst[d * 2048] = src[d];
  }
}

// ---------------------------------------------------------------- GEMM
template <int MODE>
__global__ __launch_bounds__(256, 2) void gemm_bt(
    const u16* __restrict__ A, const u16* __restrict__ Bt,
    const float* __restrict__ bias, float* __restrict__ out,
    u16* __restrict__ Qb, u16* __restrict__ Kb, u16* __restrict__ Vb,
    int M, int N, int K) {
  __shared__ u16 lA[128 * 32];
  __shared__ u16 lB[128 * 32];

  const int tid = threadIdx.x;
  const int lane = tid & 63;
  const int w = tid >> 6;
  const int wm = (w >> 1) * 64, wn = (w & 1) * 64;
  const int l15 = lane & 15, quad = lane >> 4;
  const int m0 = blockIdx.y * 128, n0 = blockIdx.x * 128;

  const int srow = lane >> 2;
  const int scol = (lane & 3) * 8;

  f32x4 acc[4][4] = {};

  for (int k0 = 0; k0 < K; k0 += 32) {
    __syncthreads();
#pragma unroll
    for (int h = 0; h < 2; h++) {
      int r = h * 64 + w * 16 + srow;
      gload_lds16(&A[(m0 + r) * K + k0 + scol], &lA[h * 2048 + w * 512 + lane * 8]);
      gload_lds16(&Bt[(n0 + r) * K + k0 + scol], &lB[h * 2048 + w * 512 + lane * 8]);
    }
    __syncthreads();

    bf16x8 af[4], bfr[4];
#pragma unroll
    for (int mi = 0; mi < 4; mi++)
      af[mi] = *(const bf16x8*)&lA[(wm + mi * 16 + l15) * 32 + quad * 8];
#pragma unroll
    for (int ni = 0; ni < 4; ni++)
      bfr[ni] = *(const bf16x8*)&lB[(wn + ni * 16 + l15) * 32 + quad * 8];
#pragma unroll
    for (int mi = 0; mi < 4; mi++)
#pragma unroll
      for (int ni = 0; ni < 4; ni++)
        acc[mi][ni] = MFMA16(af[mi], bfr[ni], acc[mi][ni]);
  }

#pragma unroll
  for (int mi = 0; mi < 4; mi++) {
#pragma unroll
    for (int ni = 0; ni < 4; ni++) {
      int n = n0 + wn + ni * 16 + l15;
      float bv = bias[n];
#pragma unroll
      for (int reg = 0; reg < 4; reg++) {
        int m = m0 + wm + mi * 16 + quad * 4 + reg;
        float v = acc[mi][ni][reg] + bv;
        if (MODE == 1) {
          out[m * N + n] = v;
        } else {
          int which = n >> 10;           // 0=q 1=k 2=v
          if (which == 1) v *= 0.18033688011112042f;  // 0.125 * log2(e)
          int hn = n & 1023;
          int hh = hn >> 6, d = hn & 63;
          int b = m >> 11, t = m & 2047;
          u16* dst = (which == 0) ? Qb : ((which == 1) ? Kb : Vb);
          dst[(((b << 4) + hh) * 2048 + t) * 64 + d] = f2b(v);
        }
      }
    }
  }
}

// ---------------------------------------------------------------- attention
// Paired split-kv. Block = (x -> (pair p, slice s), bh). 4 waves; each wave
// owns 16 q-rows of q-tile 2p (set A) AND 16 of q-tile 2p+1 (set B).
// Staged K/V fragments are shared by both sets. S^T formulation; l via
// ones-B MFMA. ns==1 -> direct Y write; else bf16 partial O + f32 l.
__global__ __launch_bounds__(256, 4) void attn_split(
    const u16* __restrict__ Qg, const u16* __restrict__ Kg,
    const u16* __restrict__ Vt, u16* __restrict__ Yg,
    u16* __restrict__ Opart, float* __restrict__ lpart) {
  __shared__ u16 lk[64 * 72];        // K tile  [kv][d]
  __shared__ u16 lvt[64 * 72];       // Vt tile [d][kv]

  const int x = 39 - blockIdx.x;     // long slices dispatch first
  const int bh = blockIdx.y;
  int p, s, ns;
  if (x < 4)       { p = x;          s = 0;           ns = 1; }
  else if (x < 12) { int r = x - 4;  p = 4 + (r >> 1);  s = r & 1;  ns = 2; }
  else if (x < 24) { int r = x - 12; p = 8 + r / 3;     s = r % 3;  ns = 3; }
  else             { int r = x - 24; p = 12 + (r >> 2); s = r & 3;  ns = 4; }
  const int kts = s * 8;
  const int ktotal = 2 * p + 2;
  const int kend = (kts + 8 < ktotal) ? (kts + 8) : ktotal;
  const int qtA = 2 * p;

  const int tid = threadIdx.x;
  const int lane = tid & 63;
  const int w = tid >> 6;
  const int l15 = lane & 15, quad = lane >> 4;
  const int base = bh * 2048 * 64;
  const int vbase = bh * 64 * 2048;

  const int sr = tid >> 3;           // 0..31
  const int sc = (tid & 7) * 8;      // 0..56

  // Q B-fragments for both q-sets (B[k=d][n=q]; lane q = w*16+l15)
  const u16* qrA = Qg + base + (qtA * 64 + w * 16 + l15) * 64;
  bf16x8 bq0A = *(const bf16x8*)&qrA[quad * 8];
  bf16x8 bq1A = *(const bf16x8*)&qrA[32 + quad * 8];
  const u16* qrB = qrA + 64 * 64;
  bf16x8 bq0B = *(const bf16x8*)&qrB[quad * 8];
  bf16x8 bq1B = *(const bf16x8*)&qrB[32 + quad * 8];

  const int qgA = qtA * 64 + w * 16 + l15;  // global q for lane's column, set A

  u16x8 onesu = {0x3F80, 0x3F80, 0x3F80, 0x3F80, 0x3F80, 0x3F80, 0x3F80, 0x3F80};
  bf16x8 ones = *(const bf16x8*)&onesu;

  const u16* kp = Kg + base;
  const u16* vp = Vt + vbase;

  // preload first tile of the slice
  u16x8 kr[2], vr[2];
  {
    int kvb = kts * 64;
#pragma unroll
    for (int h = 0; h < 2; h++) {
      int r = sr + h * 32;
      kr[h] = *(const u16x8*)&kp[(kvb + r) * 64 + sc];
      vr[h] = *(const u16x8*)&vp[r * 2048 + kvb + sc];
    }
  }

  f32x4 oA[4] = {}, oB[4] = {};
  f32x4 lA4 = {}, lB4 = {};

  for (int kt = kts; kt < kend; kt++) {
    __syncthreads();
#pragma unroll
    for (int h = 0; h < 2; h++) {
      int r = sr + h * 32;
      *(u16x8*)&lk[r * 72 + sc] = kr[h];
      *(u16x8*)&lvt[r * 72 + sc] = vr[h];
    }
    __syncthreads();
    if (kt + 1 < kend) {
      int kvb = (kt + 1) * 64;
#pragma unroll
      for (int h = 0; h < 2; h++) {
        int r = sr + h * 32;
        kr[h] = *(const u16x8*)&kp[(kvb + r) * 64 + sc];
        vr[h] = *(const u16x8*)&vp[r * 2048 + kvb + sc];
      }
    }

    const bool mA = (kt >= qtA);       // mask set A (incl. fully-masked tile)
    const bool mB = (kt == qtA + 1);   // mask set B (its diagonal)

#pragma unroll
    for (int u = 0; u < 2; u++) {
      bf16x8 paA, paB;
#pragma unroll
      for (int half = 0; half < 2; half++) {
        int nt = 2 * u + half;
        bf16x8 ak0 = *(const bf16x8*)&lk[(nt * 16 + l15) * 72 + quad * 8];
        bf16x8 ak1 = *(const bf16x8*)&lk[(nt * 16 + l15) * 72 + 32 + quad * 8];
        f32x4 stA = {};
        stA = MFMA16(ak0, bq0A, stA);
        stA = MFMA16(ak1, bq1A, stA);
        f32x4 stB = {};
        stB = MFMA16(ak0, bq0B, stB);
        stB = MFMA16(ak1, bq1B, stB);
        int kv0 = kt * 64 + nt * 16 + quad * 4;
#pragma unroll
        for (int reg = 0; reg < 4; reg++) {
          int kv = kv0 + reg;
          float svA = stA[reg];
          if (mA && kv > qgA) svA = -1e30f;
          float svB = stB[reg];
          if (mB && kv > qgA + 64) svB = -1e30f;
          paA[half * 4 + reg] = (__bf16)exp2f(svA);
          paB[half * 4 + reg] = (__bf16)exp2f(svB);
        }
      }
      lA4 = MFMA16(paA, ones, lA4);
      lB4 = MFMA16(paB, ones, lB4);
#pragma unroll
      for (int dt = 0; dt < 4; dt++) {
        const u16* vrow = &lvt[(dt * 16 + l15) * 72 + u * 32 + quad * 4];
        bf16x4 lo = *(const bf16x4*)&vrow[0];
        bf16x4 hi = *(const bf16x4*)&vrow[16];
        bf16x8 bv;
#pragma unroll
        for (int j = 0; j < 4; j++) { bv[j] = lo[j]; bv[4 + j] = hi[j]; }
        oA[dt] = MFMA16(paA, bv, oA[dt]);
        oB[dt] = MFMA16(paB, bv, oB[dt]);
      }
    }
  }

  if (ns == 1) {
    const int b = bh >> 4, hh = bh & 15;
    float invA[4], invB[4];
#pragma unroll
    for (int reg = 0; reg < 4; reg++) {
      invA[reg] = 1.0f / lA4[reg];
      invB[reg] = 1.0f / lB4[reg];
    }
#pragma unroll
    for (int dt = 0; dt < 4; dt++)
#pragma unroll
      for (int reg = 0; reg < 4; reg++) {
        int qA = qtA * 64 + w * 16 + quad * 4 + reg;
        int col = hh * 64 + dt * 16 + l15;
        Yg[(b * 2048 + qA) * 1024 + col] = f2b(oA[dt][reg] * invA[reg]);
        Yg[(b * 2048 + qA + 64) * 1024 + col] = f2b(oB[dt][reg] * invB[reg]);
      }
  } else {
    const int pidx = bh * 40 + x;
    u16* op = Opart + pidx * 8192;
#pragma unroll
    for (int dt = 0; dt < 4; dt++)
#pragma unroll
      for (int reg = 0; reg < 4; reg++) {
        int rA = w * 16 + quad * 4 + reg;
        op[rA * 64 + dt * 16 + l15] = f2b(oA[dt][reg]);
        op[(rA + 64) * 64 + dt * 16 + l15] = f2b(oB[dt][reg]);
      }
    if (l15 == 0) {
#pragma unroll
      for (int reg = 0; reg < 4; reg++) {
        int rA = w * 16 + quad * 4 + reg;
        lpart[pidx * 128 + rA] = lA4[reg];
        lpart[pidx * 128 + rA + 64] = lB4[reg];
      }
    }
  }
}

// combine <=4 partials for pairs p >= 4 (128 rows each)
__global__ __launch_bounds__(256) void attn_combine(
    const u16* __restrict__ Opart, const float* __restrict__ lpart,
    u16* __restrict__ Yg) {
  const int pp = 4 + blockIdx.x;    // pair 4..15
  const int bh = blockIdx.y;
  const int tid = threadIdx.x;
  const int row = tid >> 1;         // 0..127
  const int cg = (tid & 1) * 32;    // 0 or 32
  int xb, ns;
  if (pp < 8)       { xb = 4  + (pp - 4) * 2;  ns = 2; }
  else if (pp < 12) { xb = 12 + (pp - 8) * 3;  ns = 3; }
  else              { xb = 24 + (pp - 12) * 4; ns = 4; }

  float acc[32] = {};
  float lsum = 0.f;
  for (int i = 0; i < ns; i++) {
    int pidx = bh * 40 + xb + i;
    lsum += lpart[pidx * 128 + row];
    const u16* oprow = Opart + pidx * 8192 + row * 64 + cg;
#pragma unroll
    for (int v = 0; v < 4; v++) {
      u16x8 a = *(const u16x8*)&oprow[v * 8];
#pragma unroll
      for (int j = 0; j < 8; j++) acc[v * 8 + j] += b2f(a[j]);
    }
  }
  float inv = 1.0f / lsum;
  const int b = bh >> 4, hh = bh & 15;
  u16* y = Yg + ((long)(b * 2048 + pp * 128 + row)) * 1024 + hh * 64 + cg;
#pragma unroll
  for (int v = 0; v < 4; v++) {
    u16x8 o;
#pragma unroll
    for (int j = 0; j < 8; j++) o[j] = f2b(acc[v * 8 + j] * inv);
    *(u16x8*)&y[v * 8] = o;
  }
}

// ---------------------------------------------------------------- fallback
// (round-8 single-block-per-qt attention, for small ws_size)
__global__ __launch_bounds__(256, 4) void attn_kernel(
    const u16* __restrict__ Qg, const u16* __restrict__ Kg,
    const u16* __restrict__ Vt, u16* __restrict__ Yg) {
  __shared__ u16 lk[64 * 72];
  __shared__ u16 lvt[64 * 72];

  const int qt = 31 - blockIdx.x;
  const int bh = blockIdx.y;
  const int tid = threadIdx.x;
  const int lane = tid & 63;
  const int w = tid >> 6;
  const int l15 = lane & 15, quad = lane >> 4;
  const int qbase = qt * 64;
  const int base = bh * 2048 * 64;
  const int vbase = bh * 64 * 2048;
  const int sr = tid >> 3;
  const int sc = (tid & 7) * 8;

  const u16* qrow = Qg + base + (qbase + w * 16 + l15) * 64;
  bf16x8 bq0 = *(const bf16x8*)&qrow[quad * 8];
  bf16x8 bq1 = *(const bf16x8*)&qrow[32 + quad * 8];

  u16x8 onesu = {0x3F80, 0x3F80, 0x3F80, 0x3F80, 0x3F80, 0x3F80, 0x3F80, 0x3F80};
  bf16x8 ones = *(const bf16x8*)&onesu;

  const u16* kp = Kg + base;
  const u16* vp = Vt + vbase;

  u16x8 kr[2], vr[2];
#pragma unroll
  for (int h = 0; h < 2; h++) {
    int r = sr + h * 32;
    kr[h] = *(const u16x8*)&kp[r * 64 + sc];
    vr[h] = *(const u16x8*)&vp[r * 2048 + sc];
  }

  f32x4 oacc[4] = {};
  f32x4 lacc = {};

  for (int kt = 0; kt <= qt; kt++) {
    __syncthreads();
#pragma unroll
    for (int h = 0; h < 2; h++) {
      int r = sr + h * 32;
      *(u16x8*)&lk[r * 72 + sc] = kr[h];
      *(u16x8*)&lvt[r * 72 + sc] = vr[h];
    }
    __syncthreads();
    if (kt < qt) {
      int kvb = (kt + 1) * 64;
#pragma unroll
      for (int h = 0; h < 2; h++) {
        int r = sr + h * 32;
        kr[h] = *(const u16x8*)&kp[(kvb + r) * 64 + sc];
        vr[h] = *(const u16x8*)&vp[r * 2048 + kvb + sc];
      }
    }

    const bool diag = (kt == qt);
    const int qloc = w * 16 + l15;
#pragma unroll
    for (int u = 0; u < 2; u++) {
      bf16x8 pa;
#pragma unroll
      for (int half = 0; half < 2; half++) {
        int nt = 2 * u + half;
        bf16x8 ak0 = *(const bf16x8*)&lk[(nt * 16 + l15) * 72 + quad * 8];
        bf16x8 ak1 = *(const bf16x8*)&lk[(nt * 16 + l15) * 72 + 32 + quad * 8];
        f32x4 st = {};
        st = MFMA16(ak0, bq0, st);
        st = MFMA16(ak1, bq1, st);
#pragma unroll
        for (int reg = 0; reg < 4; reg++) {
          float sv = st[reg];
          if (diag && (nt * 16 + quad * 4 + reg) > qloc) sv = -1e30f;
          pa[half * 4 + reg] = (__bf16)exp2f(sv);
        }
      }
      lacc = MFMA16(pa, ones, lacc);
#pragma unroll
      for (int dt = 0; dt < 4; dt++) {
        const u16* vrow = &lvt[(dt * 16 + l15) * 72 + u * 32 + quad * 4];
        bf16x4 lo = *(const bf16x4*)&vrow[0];
        bf16x4 hi = *(const bf16x4*)&vrow[16];
        bf16x8 bv;
#pragma unroll
        for (int j = 0; j < 4; j++) { bv[j] = lo[j]; bv[4 + j] = hi[j]; }
        oacc[dt] = MFMA16(pa, bv, oacc[dt]);
      }
    }
  }

  const int b = bh >> 4, hh = bh & 15;
  float inv[4];
#pragma unroll
  for (int reg = 0; reg < 4; reg++) inv[reg] = 1.0f / lacc[reg];
#pragma unroll
  for (int dt = 0; dt < 4; dt++)
#pragma unroll
    for (int reg = 0; reg < 4; reg++) {
      int q = qbase + w * 16 + quad * 4 + reg;
      int col = hh * 64 + dt * 16 + l15;
      Yg[(b * 2048 + q) * 1024 + col] = f2b(oacc[dt][reg] * inv[reg]);
    }
}

// ---------------------------------------------------------------- launch
extern "C" void kernel_launch(void* const* d_in, const int* in_sizes, int n_in,
                              void* d_out, int out_size, void* d_ws, size_t ws_size,
                              hipStream_t stream) {
  const float* x      = (const float*)d_in[0];
  const float* w_attn = (const float*)d_in[1];
  const float* b_attn = (const float*)d_in[2];
  const float* w_proj = (const float*)d_in[3];
  const float* b_proj = (const float*)d_in[4];
  float* out = (float*)d_out;

  char* ws = (char*)d_ws;
  u16* wattnT = (u16*)(ws);                  //  6291456 B
  u16* wprojT = (u16*)(ws + 6291456);        //  2097152 B
  u16* xb     = (u16*)(ws + 8388608);        //  8388608 B (dead after QKV gemm)
  u16* Vt     = xb;                          //  aliases xb
  u16* Qb     = (u16*)(ws + 16777216);
  u16* Kb     = (u16*)(ws + 25165824);
  u16* Vb     = (u16*)(ws + 33554432);
  u16* Yb     = (u16*)(ws + 41943040);       //  8388608 B -> 50331648
  u16* Opart  = (u16*)(ws + 50331648);       //  1280 * 8192 u16 = 20971520 B
  float* lpart = (float*)(ws + 71303168);    //  1280 * 128 f32 = 655360 B

  const bool split = (ws_size >= 71958528ULL);

  cast_f32_bf16<<<2048, 256, 0, stream>>>(x, xb);
  transpose_f32_bf16<<<dim3(96, 32), dim3(32, 8), 0, stream>>>(w_attn, wattnT, 1024, 3072);
  transpose_f32_bf16<<<dim3(32, 32), dim3(32, 8), 0, stream>>>(w_proj, wprojT, 1024, 1024);
  gemm_bt<0><<<dim3(24, 32), 256, 0, stream>>>(xb, wattnT, b_attn, nullptr,
                                               Qb, Kb, Vb, 4096, 3072, 1024);
  transpose_v<<<dim3(16, 32), 256, 0, stream>>>(Vb, Vt);
  if (split) {
    attn_split<<<dim3(40, 32), 256, 0, stream>>>(Qb, Kb, Vt, Yb, Opart, lpart);
    attn_combine<<<dim3(12, 32), 256, 0, stream>>>(Opart, lpart, Yb);
  } else {
    attn_kernel<<<dim3(32, 32), 256, 0, stream>>>(Qb, Kb, Vt, Yb);
  }
  gemm_bt<1><<<dim3(8, 32), 256, 0, stream>>>(Yb, wprojT, b_proj, out,
                                              nullptr, nullptr, nullptr, 4096, 1024, 1024);
}